// Round 1
// baseline (810.394 us; speedup 1.0000x reference)
//
#include <hip/hip_runtime.h>

// One block (256 threads) per row of 1024 floats.
// Phase 1: float4 load, finite flags (exponent != all-ones covers NaN and Inf,
//          immune to fast-math isnan elision).
// Phase 2: block exclusive scan of finite counts (wave64 shfl scan + LDS combine).
// Phase 3: scatter survivors into LDS compaction buffer (stable order).
// Phase 4: float4 read-back, y = c*w + b where idx < count else 0, float4 store.

constexpr int SIZE = 1024;
constexpr int THREADS = 256;   // 4 elements per thread

__global__ __launch_bounds__(THREADS) void nan_compact_affine(
    const float* __restrict__ X,
    const float* __restrict__ w,
    const float* __restrict__ b,
    float* __restrict__ out)
{
    __shared__ __align__(16) float comp[SIZE];
    __shared__ int wsum[THREADS / 64];

    const int t = threadIdx.x;
    const int lane = t & 63;
    const int wave = t >> 6;
    const size_t rowoff = (size_t)blockIdx.x * SIZE;

    float4 v = reinterpret_cast<const float4*>(X + rowoff)[t];

    // finite iff exponent bits are not all ones (handles NaN and +-Inf)
    unsigned u0 = __float_as_uint(v.x);
    unsigned u1 = __float_as_uint(v.y);
    unsigned u2 = __float_as_uint(v.z);
    unsigned u3 = __float_as_uint(v.w);
    int f0 = (u0 & 0x7f800000u) != 0x7f800000u;
    int f1 = (u1 & 0x7f800000u) != 0x7f800000u;
    int f2 = (u2 & 0x7f800000u) != 0x7f800000u;
    int f3 = (u3 & 0x7f800000u) != 0x7f800000u;
    int lc = f0 + f1 + f2 + f3;

    // wave64 inclusive scan of per-thread counts
    int inc = lc;
    #pragma unroll
    for (int d = 1; d < 64; d <<= 1) {
        int nb = __shfl_up(inc, d, 64);
        if (lane >= d) inc += nb;
    }
    if (lane == 63) wsum[wave] = inc;
    __syncthreads();

    // combine the 4 wave totals (block has exactly 4 waves)
    int s0 = wsum[0], s1 = wsum[1], s2 = wsum[2], s3 = wsum[3];
    int wbase = (wave > 0 ? s0 : 0) + (wave > 1 ? s1 : 0) + (wave > 2 ? s2 : 0);
    int total = s0 + s1 + s2 + s3;

    // stable scatter of finite values into the compaction buffer
    int pos = wbase + inc - lc;   // exclusive prefix for this thread's 4 slots
    if (f0) comp[pos++] = v.x;
    if (f1) comp[pos++] = v.y;
    if (f2) comp[pos++] = v.z;
    if (f3) comp[pos++] = v.w;
    __syncthreads();

    // affine + zero-pad; comp beyond `total` is garbage but selected away
    float4 wv = reinterpret_cast<const float4*>(w)[t];
    float4 bv = reinterpret_cast<const float4*>(b)[t];
    float4 cv = reinterpret_cast<const float4*>(comp)[t];
    int i0 = t * 4;
    float4 o;
    o.x = (i0 + 0 < total) ? (cv.x * wv.x + bv.x) : 0.0f;
    o.y = (i0 + 1 < total) ? (cv.y * wv.y + bv.y) : 0.0f;
    o.z = (i0 + 2 < total) ? (cv.z * wv.z + bv.z) : 0.0f;
    o.w = (i0 + 3 < total) ? (cv.w * wv.w + bv.w) : 0.0f;
    reinterpret_cast<float4*>(out + rowoff)[t] = o;
}

extern "C" void kernel_launch(void* const* d_in, const int* in_sizes, int n_in,
                              void* d_out, int out_size, void* d_ws, size_t ws_size,
                              hipStream_t stream) {
    const float* X = (const float*)d_in[0];
    const float* w = (const float*)d_in[1];
    const float* b = (const float*)d_in[2];
    float* out = (float*)d_out;
    const int rows = in_sizes[0] / SIZE;   // 131072
    nan_compact_affine<<<rows, THREADS, 0, stream>>>(X, w, b, out);
}